// Round 4
// baseline (204.117 us; speedup 1.0000x reference)
//
#include <hip/hip_runtime.h>

#define EPS 2e-5f

using short8  = __attribute__((ext_vector_type(8))) short;
using floatx4 = __attribute__((ext_vector_type(4))) float;

// round-to-nearest-even fp32 -> bf16 bits
static __device__ inline unsigned short f2bf(float f) {
    unsigned u = __float_as_uint(f);
    u += 0x7fffu + ((u >> 16) & 1u);
    return (unsigned short)(u >> 16);
}

// ---------------------------------------------------------------------------
// MFMA 16x16x32 bf16 operand layouts (HW-verified per guide):
//   A[m][k]: lane l holds m=l&15, k=(l>>4)*8+e, e=0..7  (8 contiguous k = 16B)
//   B[k][n]: lane l holds n=l&15, k=(l>>4)*8+e
//   C/D   : lane l, reg r -> row=(l>>4)*4+r, col=l&15
//
// Pipeline (6 kernels):
//   k_setup : zero stats; W1f bf16 B-frags [j][T16][ks3][lane][8].
//   k1      : A from x directly (fp32->bf16 in-wave); MFMA GEMM per j (K=96)
//             + pool(16->8)+relu via shfl -> p1 bf16 [b][i][jj][s] + BN1 stats.
//   k_bias  : fold BN1 -> W2f bf16 frags [j][T16][ks12][lane][8];
//             bias2[j][col] = sum raw*d1.
//   k2      : 2 m-tiles/wave MFMA GEMM per j (K=384) + bias + pool(8->4)+relu
//             -> p2s bf16 [jj][l][b][i] (stage-3 A-layout) + BN2 stats.
//   k3      : per-block fold BN2 into w3 (LDS W3s/bias3); MFMA per (j;l=0..2),
//             max over l, *2^-j, relu -> act3[b][o*5+j] + BN3 stats.
//   k4      : per-block fold BN3 into fw1 (LDS, bf16); MFMA FC1 (K=320,N=16);
//             fp32 LDS tail for FC2/FC3 -> out (B,17).
// ---------------------------------------------------------------------------

__global__ void __launch_bounds__(256) k_setup(const float* __restrict__ w1,
                                               unsigned short* __restrict__ W1f,
                                               float* __restrict__ stats) {
    int gid = blockIdx.x * 256 + threadIdx.x;
    if (gid < 256) stats[gid] = 0.f;
    if (gid >= 221184) return;               // 9*16*3*512 W1 fragments
    int j  = gid / 24576;
    int r  = gid % 24576;
    int T  = r / 1536;
    int r2 = r % 1536;
    int ks = r2 / 512;
    int r3 = r2 % 512;
    int lane = r3 >> 3, e = r3 & 7;
    int n  = T * 16 + (lane & 15);
    int kk = ks * 32 + (lane >> 4) * 8 + e;
    int o = n >> 4, t = n & 15;
    int i = kk >> 4, s = kk & 15;
    int h = 1 << j;
    int d = s - t;
    float val = 0.f;
    if (d >= -3 * h && d <= 3 * h) {
        float df = (float)d / (float)h;
        #pragma unroll
        for (int m = 0; m < 7; ++m) {
            float hat = fmaxf(0.f, 1.f - fabsf(df - (float)(m - 3)));
            val += w1[(o * 6 + i) * 7 + m] * hat;
        }
        val /= (float)h;
    }
    W1f[gid] = f2bf(val);
}

__global__ void __launch_bounds__(256) k1(const float* __restrict__ x,
                                          const unsigned short* __restrict__ W1f,
                                          unsigned short* __restrict__ p1,
                                          float* __restrict__ stats1) {
    int j    = blockIdx.y;
    int wav  = threadIdx.x >> 6;
    int lane = threadIdx.x & 63;
    int msub = wav & 1, nh = wav >> 1;
    int mt   = blockIdx.x * 2 + msub;        // 16-row tile id
    int quad = lane >> 4, l15 = lane & 15;
    floatx4 z = {0.f, 0.f, 0.f, 0.f};
    floatx4 acc[8];
    #pragma unroll
    for (int T = 0; T < 8; ++T) acc[T] = z;
    const float* xr = x + (size_t)(mt * 16 + l15) * 96;
    const short8* Bj = (const short8*)W1f + (size_t)(j * 16) * 3 * 64;
    #pragma unroll
    for (int ks = 0; ks < 3; ++ks) {
        int k0 = ks * 32 + quad * 8;
        floatx4 v0 = *(const floatx4*)(xr + k0);
        floatx4 v1 = *(const floatx4*)(xr + k0 + 4);
        short8 a;
        #pragma unroll
        for (int e = 0; e < 4; ++e) {
            a[e]     = (short)f2bf(v0[e]);
            a[e + 4] = (short)f2bf(v1[e]);
        }
        #pragma unroll
        for (int T = 0; T < 8; ++T) {
            short8 b = Bj[((nh * 8 + T) * 3 + ks) * 64 + lane];
            acc[T] = __builtin_amdgcn_mfma_f32_16x16x32_bf16(a, b, acc[T], 0, 0, 0);
        }
    }
    __shared__ float ls[32];
    if (threadIdx.x < 32) ls[threadIdx.x] = 0.f;
    __syncthreads();
    int mbase = mt * 16 + quad * 4;
    int tp = l15;                            // pooled index, lanes 0..7 active
    bool act = tp < 8;
    int tpe = tp & 7;
    int base = lane & 48;
    int c0 = base + max(2 * tpe - 1, 0);
    int c1 = base + 2 * tpe;
    int c2 = base + 2 * tpe + 1;
    int c3 = base + min(2 * tpe + 2, 15);
    #pragma unroll
    for (int T = 0; T < 8; ++T) {
        int o = nh * 8 + T;
        float psum = 0.f, pss = 0.f;
        #pragma unroll
        for (int r = 0; r < 4; ++r) {
            float v  = acc[T][r];
            float mx = fmaxf(fmaxf(__shfl(v, c0, 64), __shfl(v, c1, 64)),
                             fmaxf(__shfl(v, c2, 64), __shfl(v, c3, 64)));
            mx = fmaxf(mx, 0.f);
            if (act) {
                p1[(size_t)(mbase + r) * 1152 + o * 72 + j * 8 + tp] = f2bf(mx);
                psum += mx; pss += mx * mx;
            }
        }
        #pragma unroll
        for (int m = 32; m >= 1; m >>= 1) {
            psum += __shfl_xor(psum, m, 64);
            pss  += __shfl_xor(pss,  m, 64);
        }
        if (lane == 0) {
            atomicAdd(&ls[o], psum);
            atomicAdd(&ls[16 + o], pss);
        }
    }
    __syncthreads();
    if (threadIdx.x < 16) {
        atomicAdd(&stats1[threadIdx.x], ls[threadIdx.x]);
        atomicAdd(&stats1[16 + threadIdx.x], ls[16 + threadIdx.x]);
    }
}

__global__ void __launch_bounds__(384) k_bias(const float* __restrict__ w2,
                                              const float* __restrict__ g1,
                                              const float* __restrict__ b1,
                                              const float* __restrict__ stats1,
                                              unsigned short* __restrict__ W2f,
                                              float* __restrict__ bias2,
                                              float invN1) {
    int blk = blockIdx.x;
    int j   = blk >> 8;        // 0..6
    int col = blk & 255;       // o*8 + t
    int o = col >> 3, t = col & 7;
    int k = threadIdx.x;       // 0..383 = (i*3+c)*8 + s
    int ic = k >> 3, s = k & 7;
    int i = ic / 3, c = ic % 3;
    float mu  = stats1[i] * invN1;
    float var = stats1[16 + i] * invN1 - mu * mu;
    float rsg = rsqrtf(var + EPS);
    float a1  = g1[i] * rsg;
    float d1  = b1[i] - mu * a1;
    int h = 1 << j;
    int d = s - t;
    float raw = 0.f;
    if (d >= -h && d <= h) {
        float df = (float)d / (float)h;
        #pragma unroll
        for (int m = 0; m < 3; ++m) {
            float hat = fmaxf(0.f, 1.f - fabsf(df - (float)(m - 1)));
            raw += w2[((o * 16 + i) * 3 + c) * 3 + m] * hat;
        }
        raw /= (float)h;
    }
    {
        int T    = col >> 4;
        int lane = (col & 15) + ((k >> 3) & 3) * 16;
        int ks   = k >> 5;
        int e    = k & 7;
        W2f[(((size_t)(j * 16 + T) * 12 + ks) * 64 + lane) * 8 + e] = f2bf(raw * a1);
    }
    __shared__ float red[384];
    red[k] = raw * d1;
    __syncthreads();
    if (k < 128) red[k] += red[k + 128] + red[k + 256];
    __syncthreads();
    for (int st = 64; st >= 1; st >>= 1) {
        if (k < st) red[k] += red[k + st];
        __syncthreads();
    }
    if (k == 0) bias2[j * 256 + col] = red[0];
}

__global__ void __launch_bounds__(256) k2(const unsigned short* __restrict__ p1,
                                          const unsigned short* __restrict__ W2f,
                                          const float* __restrict__ bias2,
                                          unsigned short* __restrict__ p2s,
                                          float* __restrict__ stats2,
                                          int B) {
    int j    = blockIdx.y;
    int wav  = threadIdx.x >> 6;
    int lane = threadIdx.x & 63;
    int nh   = wav & 1, mp = wav >> 1;
    int m0   = blockIdx.x * 64 + mp * 32;    // this wave: rows m0..m0+31
    int quad = lane >> 4, l15 = lane & 15;
    floatx4 z = {0.f, 0.f, 0.f, 0.f};
    floatx4 acc[2][8];
    #pragma unroll
    for (int mi = 0; mi < 2; ++mi)
        #pragma unroll
        for (int T = 0; T < 8; ++T) acc[mi][T] = z;
    const short8* Bj = (const short8*)W2f + (size_t)(j * 16) * 12 * 64;
    const unsigned short* Arow0 = p1 + (size_t)(m0 + l15) * 1152;
    const unsigned short* Arow1 = Arow0 + 16 * 1152;
    #pragma unroll
    for (int ks = 0; ks < 12; ++ks) {
        int k0 = ks * 32 + quad * 8;
        int i  = k0 / 24;
        int c  = (k0 - i * 24) >> 3;
        int off = i * 72 + (j + c) * 8;
        short8 a0 = *(const short8*)(Arow0 + off);
        short8 a1 = *(const short8*)(Arow1 + off);
        #pragma unroll
        for (int T = 0; T < 8; ++T) {
            short8 b = Bj[((nh * 8 + T) * 12 + ks) * 64 + lane];
            acc[0][T] = __builtin_amdgcn_mfma_f32_16x16x32_bf16(a0, b, acc[0][T], 0, 0, 0);
            acc[1][T] = __builtin_amdgcn_mfma_f32_16x16x32_bf16(a1, b, acc[1][T], 0, 0, 0);
        }
    }
    __shared__ float ls[64];
    if (threadIdx.x < 64) ls[threadIdx.x] = 0.f;
    __syncthreads();
    int tp  = lane & 7;                      // pooled index, tp<4 active
    bool act = tp < 4;
    int tpe = tp & 3;
    int base = lane & 56;
    int c0 = base + max(2 * tpe - 1, 0);
    int c1 = base + 2 * tpe;
    int c2 = base + 2 * tpe + 1;
    int c3 = base + min(2 * tpe + 2, 7);
    #pragma unroll
    for (int T = 0; T < 8; ++T) {
        int n = (nh * 8 + T) * 16 + l15;     // col = o*8+t
        int o = n >> 3;
        float bias = bias2[j * 256 + n];
        float psum = 0.f, pss = 0.f;
        #pragma unroll
        for (int mi = 0; mi < 2; ++mi) {
            int mbase = m0 + mi * 16 + quad * 4;
            #pragma unroll
            for (int r = 0; r < 4; ++r) {
                float v  = acc[mi][T][r] + bias;
                float mx = fmaxf(fmaxf(__shfl(v, c0, 64), __shfl(v, c1, 64)),
                                 fmaxf(__shfl(v, c2, 64), __shfl(v, c3, 64)));
                mx = fmaxf(mx, 0.f);
                if (act) {
                    // stage-3 A-fragment layout: [jj][l][b][i]
                    p2s[(((size_t)j * 4 + tp) * B + mbase + r) * 32 + o] = f2bf(mx);
                    psum += mx; pss += mx * mx;
                }
            }
        }
        #pragma unroll
        for (int m = 0; m < 5; ++m) {
            int msk = (m < 3) ? (1 << m) : (1 << (m + 1));   // 1,2,4,16,32
            psum += __shfl_xor(psum, msk, 64);
            pss  += __shfl_xor(pss,  msk, 64);
        }
        if (lane == 0 || lane == 8) {
            int oo = (nh * 8 + T) * 2 + (lane >> 3);
            atomicAdd(&ls[oo], psum);
            atomicAdd(&ls[32 + oo], pss);
        }
    }
    __syncthreads();
    if (threadIdx.x < 32) {
        atomicAdd(&stats2[threadIdx.x], ls[threadIdx.x]);
        atomicAdd(&stats2[32 + threadIdx.x], ls[32 + threadIdx.x]);
    }
}

__global__ void __launch_bounds__(256) k3(const unsigned short* __restrict__ p2s,
                                          const float* __restrict__ w3,
                                          const float* __restrict__ g2,
                                          const float* __restrict__ b2,
                                          const float* __restrict__ stats2,
                                          float* __restrict__ act3,
                                          float* __restrict__ stats3,
                                          float invN2, int B) {
    int j    = blockIdx.y;                   // 0..4
    int wav  = threadIdx.x >> 6;
    int lane = threadIdx.x & 63;
    int msub = wav & 1, nh = wav >> 1;
    int m0   = (blockIdx.x * 2 + msub) * 16;
    int quad = lane >> 4, l15 = lane & 15;
    __shared__ float a2s[32], d2s[32], bias3s[64], ls[128];
    __shared__ unsigned short W3s[6144];
    if (threadIdx.x < 128) ls[threadIdx.x] = 0.f;
    if (threadIdx.x < 32) {
        int i = threadIdx.x;
        float mu  = stats2[i] * invN2;
        float var = stats2[32 + i] * invN2 - mu * mu;
        float rsg = rsqrtf(var + EPS);
        a2s[i] = g2[i] * rsg;
        d2s[i] = b2[i] - mu * a2s[i];
    }
    __syncthreads();
    for (int idx = threadIdx.x; idx < 6144; idx += 256) {
        int e  = idx & 7;
        int ln = (idx >> 3) & 63;
        int fs = idx >> 9;                   // Tg*3+ks
        int Tg = fs / 3, ks = fs % 3;
        int n = Tg * 16 + (ln & 15);
        int i = (ln >> 4) * 8 + e;
        W3s[idx] = f2bf(w3[n * 96 + i * 3 + ks] * a2s[i]);
    }
    if (threadIdx.x < 64) {
        float s = 0.f;
        for (int i = 0; i < 32; ++i)
            #pragma unroll
            for (int kk = 0; kk < 3; ++kk)
                s = fmaf(w3[threadIdx.x * 96 + i * 3 + kk], d2s[i], s);
        bias3s[threadIdx.x] = s;
    }
    __syncthreads();
    short8 bf[2][3];
    #pragma unroll
    for (int T = 0; T < 2; ++T)
        #pragma unroll
        for (int ks = 0; ks < 3; ++ks)
            bf[T][ks] = *(const short8*)&W3s[(((nh * 2 + T) * 3 + ks) * 64 + lane) * 8];
    floatx4 z = {0.f, 0.f, 0.f, 0.f};
    floatx4 acc[2][3];
    #pragma unroll
    for (int T = 0; T < 2; ++T)
        #pragma unroll
        for (int l = 0; l < 3; ++l) acc[T][l] = z;
    #pragma unroll
    for (int ks = 0; ks < 3; ++ks) {
        int jj = j + ks;
        #pragma unroll
        for (int l = 0; l < 3; ++l) {
            const short8* ap =
                (const short8*)(p2s + ((size_t)(jj * 4 + l) * B + m0 + l15) * 32) + quad;
            short8 a = *ap;
            #pragma unroll
            for (int T = 0; T < 2; ++T)
                acc[T][l] = __builtin_amdgcn_mfma_f32_16x16x32_bf16(a, bf[T][ks],
                                                                    acc[T][l], 0, 0, 0);
        }
    }
    float inv = 1.f / (float)(1 << j);
    int mbase = m0 + quad * 4;
    #pragma unroll
    for (int T = 0; T < 2; ++T) {
        int col = nh * 32 + T * 16 + l15;    // o
        float bias = bias3s[col];
        float psum = 0.f, pss = 0.f;
        #pragma unroll
        for (int r = 0; r < 4; ++r) {
            float v = fmaxf(fmaxf(acc[T][0][r], acc[T][1][r]), acc[T][2][r]);
            v = fmaxf((v + bias) * inv, 0.f);
            act3[(size_t)(mbase + r) * 320 + col * 5 + j] = v;
            psum += v; pss += v * v;
        }
        psum += __shfl_xor(psum, 16, 64); pss += __shfl_xor(pss, 16, 64);
        psum += __shfl_xor(psum, 32, 64); pss += __shfl_xor(pss, 32, 64);
        if (quad == 0) {
            atomicAdd(&ls[col], psum);
            atomicAdd(&ls[64 + col], pss);
        }
    }
    __syncthreads();
    if (threadIdx.x < 64) {
        atomicAdd(&stats3[threadIdx.x], ls[threadIdx.x]);
        atomicAdd(&stats3[64 + threadIdx.x], ls[64 + threadIdx.x]);
    }
}

__global__ void __launch_bounds__(128) k4(const float* __restrict__ act3,
                                          const float* __restrict__ g3,
                                          const float* __restrict__ b3,
                                          const float* __restrict__ stats3,
                                          const float* __restrict__ fw1,
                                          const float* __restrict__ fb1,
                                          const float* __restrict__ fw2,
                                          const float* __restrict__ fb2,
                                          const float* __restrict__ fw3,
                                          const float* __restrict__ fb3,
                                          float* __restrict__ out,
                                          float invN3) {
    __shared__ float a3s[64], d3s[64];
    __shared__ unsigned short W1s[5120];     // fw1 x BN3-scale, B-frag layout
    __shared__ float fw2s[256], fw3s[272], fb2s[16], fb3s[17], fb1f[16];
    __shared__ float hbuf[2][16][17];
    int tid = threadIdx.x;
    if (tid < 64) {
        float mu  = stats3[tid] * invN3;
        float var = stats3[64 + tid] * invN3 - mu * mu;
        float rsg = rsqrtf(var + EPS);
        a3s[tid] = g3[tid] * rsg;
        d3s[tid] = b3[tid] - mu * a3s[tid];
    }
    __syncthreads();
    for (int idx = tid; idx < 5120; idx += 128) {
        int e  = idx & 7;
        int ln = (idx >> 3) & 63;
        int ks = idx >> 9;
        int n  = ln & 15;
        int k  = ks * 32 + (ln >> 4) * 8 + e;
        W1s[idx] = f2bf(fw1[n * 320 + k] * a3s[k / 5]);
    }
    for (int idx = tid; idx < 256; idx += 128) fw2s[idx] = fw2[idx];
    for (int idx = tid; idx < 272; idx += 128) fw3s[idx] = fw3[idx];
    if (tid < 16) fb2s[tid] = fb2[tid];
    if (tid < 17) fb3s[tid] = fb3[tid];
    if (tid < 16) {                          // fb1 + sum fw1*d3 (BN shift fold)
        float s = fb1[tid];
        for (int o = 0; o < 64; ++o) {
            float dd = d3s[o];
            #pragma unroll
            for (int jj = 0; jj < 5; ++jj)
                s = fmaf(fw1[tid * 320 + o * 5 + jj], dd, s);
        }
        fb1f[tid] = s;
    }
    __syncthreads();
    int wav = tid >> 6, lane = tid & 63;
    int quad = lane >> 4, l15 = lane & 15;
    int mt = blockIdx.x * 2 + wav;
    const float* ar = act3 + (size_t)(mt * 16 + l15) * 320;
    floatx4 acc = {0.f, 0.f, 0.f, 0.f};
    #pragma unroll
    for (int ks = 0; ks < 10; ++ks) {
        int k0 = ks * 32 + quad * 8;
        floatx4 v0 = *(const floatx4*)(ar + k0);
        floatx4 v1 = *(const floatx4*)(ar + k0 + 4);
        short8 a;
        #pragma unroll
        for (int e = 0; e < 4; ++e) {
            a[e]     = (short)f2bf(v0[e]);
            a[e + 4] = (short)f2bf(v1[e]);
        }
        short8 b = *(const short8*)&W1s[(ks * 64 + lane) * 8];
        acc = __builtin_amdgcn_mfma_f32_16x16x32_bf16(a, b, acc, 0, 0, 0);
    }
    #pragma unroll
    for (int r = 0; r < 4; ++r)
        hbuf[wav][quad * 4 + r][l15] = acc[r] + fb1f[l15];
    __syncthreads();
    if (lane < 16) {
        int row = l15;
        float hv[16];
        #pragma unroll
        for (int n = 0; n < 16; ++n) hv[n] = hbuf[wav][row][n];
        float h2[16];
        #pragma unroll
        for (int f2 = 0; f2 < 16; ++f2) {
            float s = fb2s[f2];
            #pragma unroll
            for (int n = 0; n < 16; ++n) s = fmaf(fw2s[f2 * 16 + n], hv[n], s);
            h2[f2] = s;
        }
        float* orow = out + (size_t)(mt * 16 + row) * 17;
        #pragma unroll
        for (int f3 = 0; f3 < 17; ++f3) {
            float s = fb3s[f3];
            #pragma unroll
            for (int n = 0; n < 16; ++n) s = fmaf(fw3s[f3 * 16 + n], h2[n], s);
            orow[f3] = s;
        }
    }
}

extern "C" void kernel_launch(void* const* d_in, const int* in_sizes, int n_in,
                              void* d_out, int out_size, void* d_ws, size_t ws_size,
                              hipStream_t stream) {
    (void)n_in; (void)out_size; (void)ws_size;
    const float* x   = (const float*)d_in[0];
    const float* w1  = (const float*)d_in[1];
    const float* w2  = (const float*)d_in[2];
    const float* w3  = (const float*)d_in[3];
    const float* g1  = (const float*)d_in[4];
    const float* b1  = (const float*)d_in[5];
    const float* g2  = (const float*)d_in[6];
    const float* b2  = (const float*)d_in[7];
    const float* g3  = (const float*)d_in[8];
    const float* b3  = (const float*)d_in[9];
    const float* fw1 = (const float*)d_in[10];
    const float* fb1 = (const float*)d_in[11];
    const float* fw2 = (const float*)d_in[12];
    const float* fb2 = (const float*)d_in[13];
    const float* fw3 = (const float*)d_in[14];
    const float* fb3 = (const float*)d_in[15];
    float* out = (float*)d_out;

    int B = in_sizes[0] / 96;                 // 4096

    char* wsb = (char*)d_ws;
    float*          stats  = (float*)wsb;                     // 256 f
    unsigned short* W1f    = (unsigned short*)(wsb + 1024);   // 221184 us
    unsigned short* W2f    = W1f + 221184;                    // 688128 us
    float*          bias2  = (float*)(W2f + 688128);          // 1792 f
    unsigned short* p1     = (unsigned short*)(bias2 + 1792); // B*1152 us
    unsigned short* p2s    = p1 + (size_t)B * 1152;           // B*896 us
    float*          act3   = (float*)(p2s + (size_t)B * 896); // B*320 f

    float* stats1 = stats;
    float* stats2 = stats + 32;
    float* stats3 = stats + 96;

    float invN1 = 1.f / (float)(B * 72);
    float invN2 = 1.f / (float)(B * 28);
    float invN3 = 1.f / (float)(B * 5);

    k_setup<<<864, 256, 0, stream>>>(w1, W1f, stats);
    k1<<<dim3(B / 32, 9), 256, 0, stream>>>(x, W1f, p1, stats1);
    k_bias<<<7 * 256, 384, 0, stream>>>(w2, g1, b1, stats1, W2f, bias2, invN1);
    k2<<<dim3(B / 64, 7), 256, 0, stream>>>(p1, W2f, bias2, p2s, stats2, B);
    k3<<<dim3(B / 32, 5), 256, 0, stream>>>(p2s, w3, g2, b2, stats2, act3, stats3,
                                            invN2, B);
    k4<<<B / 32, 128, 0, stream>>>(act3, g3, b3, stats3, fw1, fb1, fw2, fb2, fw3, fb3,
                                   out, invN3);
}